// Round 7
// baseline (236.345 us; speedup 1.0000x reference)
//
#include <hip/hip_runtime.h>

// ---------------- problem constants ----------------
#define HHEADS 16
#define R1 4
#define R2 8
#define HD 64
#define CDIM 1024
#define NSEQ 2048
#define BATCH 2
#define NPROJ 1408            // 64 q1 + 64 k1 + 128 q2 + 128 k2 + 1024 v
#define MROWS (BATCH * NSEQ)  // 4096
#define SCALE 0.17677669529663687f   // (R1*R2)^-0.5
#define SCALE_LOG2E 0.2550348612f    // SCALE * log2(e): scores in log2 domain

typedef __attribute__((ext_vector_type(8))) short bf16x8;
typedef __attribute__((ext_vector_type(4))) float f32x4;
typedef __attribute__((ext_vector_type(4))) unsigned int u32x4;

// ---------------- bf16 helpers (raw ushort representation) ----------------
__device__ __forceinline__ float bflo(unsigned u) { return __uint_as_float(u << 16); }
__device__ __forceinline__ float bfhi(unsigned u) { return __uint_as_float(u & 0xffff0000u); }
__device__ __forceinline__ unsigned short f2bfr(float f) {
  unsigned u = __float_as_uint(f);
  u += 0x7fffu + ((u >> 16) & 1u);
  return (unsigned short)(u >> 16);
}
__device__ __forceinline__ unsigned pack2(float a, float b) {
  return (unsigned)f2bfr(a) | ((unsigned)f2bfr(b) << 16);
}
// hardware packed f32x2 -> bf16x2 (RNE), single instruction (T12 recipe)
__device__ __forceinline__ unsigned cvtpk(float a, float b) {
  unsigned r;
  asm("v_cvt_pk_bf16_f32 %0, %1, %2" : "=v"(r) : "v"(a), "v"(b));
  return r;
}
// raw v_exp_f32 = 2^x (scores are kept in log2 domain)
__device__ __forceinline__ float exp2fast(float x) {
#if __has_builtin(__builtin_amdgcn_exp2f)
  return __builtin_amdgcn_exp2f(x);
#else
  float r;
  asm("v_exp_f32 %0, %1" : "=v"(r) : "v"(x));
  return r;
#endif
}

// ---------------- f32 -> bf16 conversion (vectorized) ----------------
__global__ void cvt_kernel(const float* __restrict__ src,
                           unsigned short* __restrict__ dst, int nvec) {
  for (int i = blockIdx.x * blockDim.x + threadIdx.x; i < nvec;
       i += gridDim.x * blockDim.x) {
    const float4 v = ((const float4*)src)[i];
    ushort4 o;
    o.x = f2bfr(v.x);
    o.y = f2bfr(v.y);
    o.z = f2bfr(v.z);
    o.w = f2bfr(v.w);
    ((ushort4*)dst)[i] = o;
  }
}

// ---------------- async global->LDS (16B per lane) ----------------
__device__ __forceinline__ void gld_lds16(const void* g, void* l) {
  __builtin_amdgcn_global_load_lds(
      (const __attribute__((address_space(1))) void*)g,
      (__attribute__((address_space(3))) void*)l, 16, 0, 0);
}

// ---------------- bf16 GEMM: C[M][N] = A[M][K] * Bw[N][K]^T ----------------
template <int OUTMODE>
__global__ __launch_bounds__(256) void gemm_bt(
    const unsigned short* __restrict__ A, const unsigned short* __restrict__ Bw,
    unsigned short* __restrict__ Cb, float* __restrict__ Cf,
    const float* __restrict__ bias, int M, int N, int K) {
  __shared__ unsigned short As[128 * 32];
  __shared__ unsigned short Bs[128 * 32];
  const int tid = threadIdx.x;
  const long brow = (long)blockIdx.y * 128;
  const long bcol = (long)blockIdx.x * 128;
  const int w = tid >> 6, lane = tid & 63;
  const int wr = w >> 1, wc = w & 1;
  const int lr = lane & 15, kg = lane >> 4;

  f32x4 acc[4][4];
#pragma unroll
  for (int m = 0; m < 4; ++m)
#pragma unroll
    for (int n = 0; n < 4; ++n) acc[m][n] = (f32x4){0.f, 0.f, 0.f, 0.f};

  const int off0 = tid * 16;
  const int row0 = off0 >> 6;
  const int kel0 = (off0 & 63) >> 1;

  const int nk = K >> 5;
  for (int kt = 0; kt < nk; ++kt) {
    const long kbase = (long)kt * 32 + kel0;
    gld_lds16(A + (brow + row0) * K + kbase, (char*)As + off0);
    gld_lds16(A + (brow + 64 + row0) * K + kbase, (char*)As + 4096 + off0);
    gld_lds16(Bw + (bcol + row0) * K + kbase, (char*)Bs + off0);
    gld_lds16(Bw + (bcol + 64 + row0) * K + kbase, (char*)Bs + 4096 + off0);
    __syncthreads();

    bf16x8 af[4], bfg[4];
#pragma unroll
    for (int m = 0; m < 4; ++m)
      af[m] = *(const bf16x8*)(As + (wr * 64 + m * 16 + lr) * 32 + kg * 8);
#pragma unroll
    for (int n = 0; n < 4; ++n)
      bfg[n] = *(const bf16x8*)(Bs + (wc * 64 + n * 16 + lr) * 32 + kg * 8);
#pragma unroll
    for (int m = 0; m < 4; ++m)
#pragma unroll
      for (int n = 0; n < 4; ++n)
        acc[m][n] = __builtin_amdgcn_mfma_f32_16x16x32_bf16(af[m], bfg[n],
                                                            acc[m][n], 0, 0, 0);
    __syncthreads();
  }

#pragma unroll
  for (int m = 0; m < 4; ++m) {
#pragma unroll
    for (int i = 0; i < 4; ++i) {
      const long r = brow + wr * 64 + m * 16 + kg * 4 + i;
#pragma unroll
      for (int n = 0; n < 4; ++n) {
        const long c = bcol + wc * 64 + n * 16 + lr;
        const float v = acc[m][n][i];
        if (OUTMODE == 1) {
          Cf[r * N + c] = v + bias[c];
        } else {
          Cb[r * N + c] = f2bfr(v);
        }
      }
    }
  }
}

// ---------------- kron feature build: qf/kf[bh][n][32] -------------------
// qf[r1*8+r2] = q1[r1]*q2[r2]*SCALE*log2e ; kf[r1*8+r2] = k1[r1]*k2[r2]
__global__ __launch_bounds__(256) void kron_kernel(
    const unsigned short* __restrict__ proj, unsigned short* __restrict__ qf,
    unsigned short* __restrict__ kf) {
  const int bh = blockIdx.x, b = bh >> 4, h = bh & 15;
  const int n = blockIdx.y * 256 + threadIdx.x;
  const unsigned short* row = proj + ((size_t)(b * NSEQ + n)) * NPROJ;
  float q1v[4], k1v[4], q2v[8], k2v[8];
  {
    const uint2 a = *(const uint2*)(row + h * 4);
    q1v[0] = bflo(a.x); q1v[1] = bfhi(a.x); q1v[2] = bflo(a.y); q1v[3] = bfhi(a.y);
    const uint2 c = *(const uint2*)(row + 64 + h * 4);
    k1v[0] = bflo(c.x); k1v[1] = bfhi(c.x); k1v[2] = bflo(c.y); k1v[3] = bfhi(c.y);
    const uint4 d = *(const uint4*)(row + 128 + h * 8);
    q2v[0] = bflo(d.x); q2v[1] = bfhi(d.x); q2v[2] = bflo(d.y); q2v[3] = bfhi(d.y);
    q2v[4] = bflo(d.z); q2v[5] = bfhi(d.z); q2v[6] = bflo(d.w); q2v[7] = bfhi(d.w);
    const uint4 e = *(const uint4*)(row + 256 + h * 8);
    k2v[0] = bflo(e.x); k2v[1] = bfhi(e.x); k2v[2] = bflo(e.y); k2v[3] = bfhi(e.y);
    k2v[4] = bflo(e.z); k2v[5] = bfhi(e.z); k2v[6] = bflo(e.w); k2v[7] = bfhi(e.w);
  }
  unsigned short* oq = qf + ((size_t)bh * NSEQ + n) * 32;
  unsigned short* ok = kf + ((size_t)bh * NSEQ + n) * 32;
#pragma unroll
  for (int i = 0; i < 4; ++i) {
    const float qs = q1v[i] * SCALE_LOG2E;
    uint4 uq, uk;
    uq.x = pack2(qs * q2v[0], qs * q2v[1]);
    uq.y = pack2(qs * q2v[2], qs * q2v[3]);
    uq.z = pack2(qs * q2v[4], qs * q2v[5]);
    uq.w = pack2(qs * q2v[6], qs * q2v[7]);
    uk.x = pack2(k1v[i] * k2v[0], k1v[i] * k2v[1]);
    uk.y = pack2(k1v[i] * k2v[2], k1v[i] * k2v[3]);
    uk.z = pack2(k1v[i] * k2v[4], k1v[i] * k2v[5]);
    uk.w = pack2(k1v[i] * k2v[6], k1v[i] * k2v[7]);
    *(uint4*)(oq + i * 8) = uq;
    *(uint4*)(ok + i * 8) = uk;
  }
}

// ---------------- V transpose: vt[bh][d][n] = proj[b,n][384+h*64+d] -------
__global__ __launch_bounds__(256) void vtrans_kernel(
    const unsigned short* __restrict__ proj, unsigned short* __restrict__ vt) {
  const int bh = blockIdx.y, b = bh >> 4, h = bh & 15;
  const int n0 = blockIdx.x * 64;
  const int tid = threadIdx.x;
#pragma unroll
  for (int it = 0; it < 2; ++it) {
    const int c = tid + it * 256;
    const int dd = c & 63;
    const int nn = (c >> 6) * 8;
    const unsigned short* src =
        proj + ((size_t)(b * NSEQ + n0 + nn)) * NPROJ + 384 + h * 64 + dd;
    unsigned short tmp[8];
#pragma unroll
    for (int j = 0; j < 8; ++j) tmp[j] = src[(size_t)j * NPROJ];
    uint4 u;
    u.x = (unsigned)tmp[0] | ((unsigned)tmp[1] << 16);
    u.y = (unsigned)tmp[2] | ((unsigned)tmp[3] << 16);
    u.z = (unsigned)tmp[4] | ((unsigned)tmp[5] << 16);
    u.w = (unsigned)tmp[6] | ((unsigned)tmp[7] << 16);
    *(uint4*)(vt + ((size_t)bh * 64 + dd) * NSEQ + n0 + nn) = u;
  }
}

// ---------------- MFMA flash attention: 4-wave blocks, in-block split-K ----
// 1408 blocks x 4 waves = 5632 waves, each <=16 key-tiles:
//  j in [0,32):  heavy block, qb = 63-j, 4 chunks (waves = chunks), LDS merge
//  j in [32,40): mid block m=j-32: item A qb=31-2m (waves 0,1), item B
//                qb=30-2m (waves 2,3), 2 chunks each, two LDS merges
//  j in [40,44): light block t=j-40: wave w -> qb = 15-(4t+w), direct write
// Non-leader chunks write unnormalized bf16 O + (m,l) to LDS (row pad 68
// kills the q-stride bank conflict); one barrier; leader does LSE merge.
// XCD affinity: bid&7 pins all 44 blocks of a head to one XCD (~1MB L2 set).
__global__ __launch_bounds__(256, 5) void attn_split(
    const unsigned short* __restrict__ qf, const unsigned short* __restrict__ kf,
    const unsigned short* __restrict__ vt, unsigned short* __restrict__ ao) {
  __shared__ unsigned short o_part[3][32][68];
  __shared__ float st_part[3][32][2];

  const int bid = blockIdx.x;
  const int xcd = bid & 7;
  const int idx = bid >> 3;        // [0,176) per XCD
  const int g = idx / 44;          // head group [0,4)
  const int j = idx - g * 44;      // [0,44)
  const int bh = g * 8 + xcd;      // all 44 blocks of bh on one XCD
  const int w = threadIdx.x >> 6;
  const int lane = threadIdx.x & 63;

  int qb, nw, c;
  if (j < 32) {
    qb = 63 - j; nw = 4; c = w;
  } else if (j < 40) {
    const int m = j - 32;
    nw = 2;
    if (w < 2) { qb = 31 - 2 * m; c = w; }
    else       { qb = 30 - 2 * m; c = w - 2; }
  } else {
    const int t = j - 40;
    qb = 15 - (t * 4 + w); nw = 1; c = 0;
  }
  const int T = qb + 1;                       // total key tiles for this qb
  const int tb = (c * T) / nw, te = ((c + 1) * T) / nw;
  const int nt = te - tb;                     // tiles in this chunk (>=1)
  const int k_lo = tb * 32;
  const bool domask = (c == nw - 1);
  const bool is_leader = (nw > 1) && (c == 0);
  const bool is_partial = (nw > 1) && (c > 0);
  const int slot = w - 1;                     // partial waves: LDS slot
  const int s_begin = (nw == 4) ? 0 : w;      // leader's slot range
  const int s_end = (nw == 4) ? 3 : w + 1;

  const int qbase = qb * 32;
  const int lr = lane & 15, kg = lane >> 4;
  const int b = bh >> 4, h = bh & 15;
  const int q0 = qbase + lr;
  const int q1 = qbase + 16 + lr;

  const unsigned short* qfh = qf + (size_t)bh * NSEQ * 32;
  const unsigned short* kfh = kf + (size_t)bh * NSEQ * 32 + (size_t)k_lo * 32;
  const unsigned short* vth = vt + (size_t)bh * 64 * NSEQ + k_lo;

  const bf16x8 qA = *(const bf16x8*)(qfh + q0 * 32 + kg * 8);
  const bf16x8 qB = *(const bf16x8*)(qfh + q1 * 32 + kg * 8);
  const int krow = (lr >> 2) * 8 + (lr & 3);  // permuted key row for A-frag
  const int kof0 = krow * 32 + kg * 8;
  const int kof1 = kof0 + 4 * 32;
  const int vof0 = (0 * 16 + lr) * NSEQ + kg * 8;
  const int vof1 = (1 * 16 + lr) * NSEQ + kg * 8;
  const int vof2 = (2 * 16 + lr) * NSEQ + kg * 8;
  const int vof3 = (3 * 16 + lr) * NSEQ + kg * 8;
  const f32x4 zero = (f32x4){0.f, 0.f, 0.f, 0.f};

  f32x4 oA[4], oB[4];
#pragma unroll
  for (int dt = 0; dt < 4; ++dt) { oA[dt] = zero; oB[dt] = zero; }
  float mA = -1e30f, mB = -1e30f, lAs = 0.f, lBs = 0.f;

  // prime the pipeline: tile 0 fragments
  bf16x8 ck0 = *(const bf16x8*)(kfh + kof0);
  bf16x8 ck1 = *(const bf16x8*)(kfh + kof1);
  bf16x8 cv0 = *(const bf16x8*)(vth + vof0);
  bf16x8 cv1 = *(const bf16x8*)(vth + vof1);
  bf16x8 cv2 = *(const bf16x8*)(vth + vof2);
  bf16x8 cv3 = *(const bf16x8*)(vth + vof3);

  for (int kt = 0; kt < nt; ++kt) {
    // ---- issue next tile's loads (clamped; last iter re-loads, harmless)
    const int kn = (kt + 1 < nt ? kt + 1 : nt - 1) * 32;
    const bf16x8 nk0 = *(const bf16x8*)(kfh + kn * 32 + kof0);
    const bf16x8 nk1 = *(const bf16x8*)(kfh + kn * 32 + kof1);
    const bf16x8 nv0 = *(const bf16x8*)(vth + vof0 + kn);
    const bf16x8 nv1 = *(const bf16x8*)(vth + vof1 + kn);
    const bf16x8 nv2 = *(const bf16x8*)(vth + vof2 + kn);
    const bf16x8 nv3 = *(const bf16x8*)(vth + vof3 + kn);

    // ---- scores (log2 domain): s{A,B}0[i] = S[key k_lo+kt*32+kg*8+i][q]
    f32x4 sA0 = __builtin_amdgcn_mfma_f32_16x16x32_bf16(ck0, qA, zero, 0, 0, 0);
    f32x4 sA1 = __builtin_amdgcn_mfma_f32_16x16x32_bf16(ck1, qA, zero, 0, 0, 0);
    f32x4 sB0 = __builtin_amdgcn_mfma_f32_16x16x32_bf16(ck0, qB, zero, 0, 0, 0);
    f32x4 sB1 = __builtin_amdgcn_mfma_f32_16x16x32_bf16(ck1, qB, zero, 0, 0, 0);

    if (domask && kt == nt - 1) {  // diagonal tile: causal mask
      const int kb = k_lo + kt * 32 + kg * 8;
#pragma unroll
      for (int i = 0; i < 4; ++i) {
        if (kb + i > q0) sA0[i] = -1e30f;
        if (kb + 4 + i > q0) sA1[i] = -1e30f;
        if (kb + i > q1) sB0[i] = -1e30f;
        if (kb + 4 + i > q1) sB1[i] = -1e30f;
      }
    }

    // ---- lane-local max check; cross-lane reduce ONLY on growth
    const float mxA = fmaxf(fmaxf(fmaxf(sA0[0], sA0[1]), fmaxf(sA0[2], sA0[3])),
                            fmaxf(fmaxf(sA1[0], sA1[1]), fmaxf(sA1[2], sA1[3])));
    const float mxB = fmaxf(fmaxf(fmaxf(sB0[0], sB0[1]), fmaxf(sB0[2], sB0[3])),
                            fmaxf(fmaxf(sB1[0], sB1[1]), fmaxf(sB1[2], sB1[3])));
    const bool ok = (mxA <= mA + 8.f) && (mxB <= mB + 8.f);
    if (!__all(ok)) {
      float rA = fmaxf(mxA, __shfl_xor(mxA, 16));
      rA = fmaxf(rA, __shfl_xor(rA, 32));
      float rB = fmaxf(mxB, __shfl_xor(mxB, 16));
      rB = fmaxf(rB, __shfl_xor(rB, 32));
      const float nmA = fmaxf(mA, rA), nmB = fmaxf(mB, rB);
      const float cA = exp2fast(mA - nmA), cB = exp2fast(mB - nmB);
      mA = nmA; mB = nmB;
      lAs *= cA; lBs *= cB;
#pragma unroll
      for (int dt = 0; dt < 4; ++dt) {
        oA[dt][0] *= cA; oA[dt][1] *= cA; oA[dt][2] *= cA; oA[dt][3] *= cA;
        oB[dt][0] *= cB; oB[dt][1] *= cB; oB[dt][2] *= cB; oB[dt][3] *= cB;
      }
    }

    const float a0 = exp2fast(sA0[0] - mA), a1 = exp2fast(sA0[1] - mA);
    const float a2 = exp2fast(sA0[2] - mA), a3 = exp2fast(sA0[3] - mA);
    const float a4 = exp2fast(sA1[0] - mA), a5 = exp2fast(sA1[1] - mA);
    const float a6 = exp2fast(sA1[2] - mA), a7 = exp2fast(sA1[3] - mA);
    const float b0 = exp2fast(sB0[0] - mB), b1 = exp2fast(sB0[1] - mB);
    const float b2 = exp2fast(sB0[2] - mB), b3 = exp2fast(sB0[3] - mB);
    const float b4 = exp2fast(sB1[0] - mB), b5 = exp2fast(sB1[1] - mB);
    const float b6 = exp2fast(sB1[2] - mB), b7 = exp2fast(sB1[3] - mB);
    lAs += ((a0 + a1) + (a2 + a3)) + ((a4 + a5) + (a6 + a7));
    lBs += ((b0 + b1) + (b2 + b3)) + ((b4 + b5) + (b6 + b7));

    union { u32x4 u; bf16x8 hv; } pA, pB;
    pA.u = (u32x4){cvtpk(a0, a1), cvtpk(a2, a3), cvtpk(a4, a5), cvtpk(a6, a7)};
    pB.u = (u32x4){cvtpk(b0, b1), cvtpk(b2, b3), cvtpk(b4, b5), cvtpk(b6, b7)};

    oA[0] = __builtin_amdgcn_mfma_f32_16x16x32_bf16(cv0, pA.hv, oA[0], 0, 0, 0);
    oB[0] = __builtin_amdgcn_mfma_f32_16x16x32_bf16(cv0, pB.hv, oB[0], 0, 0, 0);
    oA[1] = __builtin_amdgcn_mfma_f32_16x16x32_bf16(cv1, pA.hv, oA[1], 0, 0, 0);
    oB[1] = __builtin_amdgcn_mfma_f32_16x16x32_bf16(cv1, pB.hv, oB[1], 0, 0, 0);
    oA[2] = __builtin_amdgcn_mfma_f32_16x16x32_bf16(cv2, pA.hv, oA[2], 0, 0, 0);
    oB[2] = __builtin_amdgcn_mfma_f32_16x16x32_bf16(cv2, pB.hv, oB[2], 0, 0, 0);
    oA[3] = __builtin_amdgcn_mfma_f32_16x16x32_bf16(cv3, pA.hv, oA[3], 0, 0, 0);
    oB[3] = __builtin_amdgcn_mfma_f32_16x16x32_bf16(cv3, pB.hv, oB[3], 0, 0, 0);

    ck0 = nk0; ck1 = nk1;
    cv0 = nv0; cv1 = nv1; cv2 = nv2; cv3 = nv3;
  }

  // per-q softmax denominator (reduce partial lsum across kg groups)
  float ltA = lAs + __shfl_xor(lAs, 16);
  ltA += __shfl_xor(ltA, 32);
  float ltB = lBs + __shfl_xor(lBs, 16);
  ltB += __shfl_xor(ltB, 32);

  if (is_partial) {  // write unnormalized bf16 O + (m,l) to LDS
#pragma unroll
    for (int dt = 0; dt < 4; ++dt) {
      uint2 ua, ub;
      ua.x = pack2(oA[dt][0], oA[dt][1]);
      ua.y = pack2(oA[dt][2], oA[dt][3]);
      ub.x = pack2(oB[dt][0], oB[dt][1]);
      ub.y = pack2(oB[dt][2], oB[dt][3]);
      *(uint2*)(&o_part[slot][lr][dt * 16 + kg * 4]) = ua;
      *(uint2*)(&o_part[slot][16 + lr][dt * 16 + kg * 4]) = ub;
    }
    if (kg == 0) {
      st_part[slot][lr][0] = mA;
      st_part[slot][lr][1] = ltA;
      st_part[slot][16 + lr][0] = mB;
      st_part[slot][16 + lr][1] = ltB;
    }
  }
  __syncthreads();

  if (is_leader) {  // LSE merge of own chunk + slots [s_begin, s_end)
    float M_A = mA, M_B = mB;
    for (int s = s_begin; s < s_end; ++s) {
      M_A = fmaxf(M_A, st_part[s][lr][0]);
      M_B = fmaxf(M_B, st_part[s][16 + lr][0]);
    }
    const float f0A = exp2fast(mA - M_A), f0B = exp2fast(mB - M_B);
    float L_A = ltA * f0A, L_B = ltB * f0B;
#pragma unroll
    for (int dt = 0; dt < 4; ++dt) {
      oA[dt][0] *= f0A; oA[dt][1] *= f0A; oA[dt][2] *= f0A; oA[dt][3] *= f0A;
      oB[dt][0] *= f0B; oB[dt][1] *= f0B; oB[dt][2] *= f0B; oB[dt][3] *= f0B;
    }
    for (int s = s_begin; s < s_end; ++s) {
      const float fsA = exp2fast(st_part[s][lr][0] - M_A);
      const float fsB = exp2fast(st_part[s][16 + lr][0] - M_B);
      L_A += st_part[s][lr][1] * fsA;
      L_B += st_part[s][16 + lr][1] * fsB;
#pragma unroll
      for (int dt = 0; dt < 4; ++dt) {
        const uint2 ua = *(const uint2*)(&o_part[s][lr][dt * 16 + kg * 4]);
        oA[dt][0] += bflo(ua.x) * fsA; oA[dt][1] += bfhi(ua.x) * fsA;
        oA[dt][2] += bflo(ua.y) * fsA; oA[dt][3] += bfhi(ua.y) * fsA;
        const uint2 ub = *(const uint2*)(&o_part[s][16 + lr][dt * 16 + kg * 4]);
        oB[dt][0] += bflo(ub.x) * fsB; oB[dt][1] += bfhi(ub.x) * fsB;
        oB[dt][2] += bflo(ub.y) * fsB; oB[dt][3] += bfhi(ub.y) * fsB;
      }
    }
    const float invA = 1.f / L_A, invB = 1.f / L_B;
    unsigned short* pAo = ao + ((size_t)(b * NSEQ + q0)) * CDIM + h * 64 + kg * 4;
    unsigned short* pBo = ao + ((size_t)(b * NSEQ + q1)) * CDIM + h * 64 + kg * 4;
#pragma unroll
    for (int dt = 0; dt < 4; ++dt) {
      uint2 ua, ub;
      ua.x = pack2(oA[dt][0] * invA, oA[dt][1] * invA);
      ua.y = pack2(oA[dt][2] * invA, oA[dt][3] * invA);
      ub.x = pack2(oB[dt][0] * invB, oB[dt][1] * invB);
      ub.y = pack2(oB[dt][2] * invB, oB[dt][3] * invB);
      *(uint2*)(pAo + dt * 16) = ua;
      *(uint2*)(pBo + dt * 16) = ub;
    }
  } else if (nw == 1) {  // light items: direct normalized write
    const float invA = 1.f / ltA, invB = 1.f / ltB;
    unsigned short* pAo = ao + ((size_t)(b * NSEQ + q0)) * CDIM + h * 64 + kg * 4;
    unsigned short* pBo = ao + ((size_t)(b * NSEQ + q1)) * CDIM + h * 64 + kg * 4;
#pragma unroll
    for (int dt = 0; dt < 4; ++dt) {
      uint2 ua, ub;
      ua.x = pack2(oA[dt][0] * invA, oA[dt][1] * invA);
      ua.y = pack2(oA[dt][2] * invA, oA[dt][3] * invA);
      ub.x = pack2(oB[dt][0] * invB, oB[dt][1] * invB);
      ub.y = pack2(oB[dt][2] * invB, oB[dt][3] * invB);
      *(uint2*)(pAo + dt * 16) = ua;
      *(uint2*)(pBo + dt * 16) = ub;
    }
  }
}

// ---------------- launch ----------------
extern "C" void kernel_launch(void* const* d_in, const int* in_sizes, int n_in,
                              void* d_out, int out_size, void* d_ws,
                              size_t ws_size, hipStream_t stream) {
  (void)in_sizes; (void)n_in; (void)out_size; (void)ws_size;
  const float* x   = (const float*)d_in[0];
  const float* Wq1 = (const float*)d_in[1];
  const float* Wk1 = (const float*)d_in[2];
  const float* Wq2 = (const float*)d_in[3];
  const float* Wk2 = (const float*)d_in[4];
  const float* Wv  = (const float*)d_in[5];
  const float* Wo  = (const float*)d_in[6];
  const float* bo  = (const float*)d_in[7];
  float* out = (float*)d_out;

  char* ws = (char*)d_ws;
  unsigned short* xb   = (unsigned short*)(ws);              // 8 MB (reused as ao)
  unsigned short* Wall = (unsigned short*)(ws + 8388608);    // 2,883,584 B
  unsigned short* Wob  = (unsigned short*)(ws + 11272192);   // 2 MB
  unsigned short* proj = (unsigned short*)(ws + 13369344);   // 11,534,336 B
  unsigned short* qf   = (unsigned short*)(ws + 24903680);   // 4 MB
  unsigned short* kf   = (unsigned short*)(ws + 29097984);   // 4 MB
  unsigned short* vt   = (unsigned short*)(ws + 33292288);   // 8 MB
  unsigned short* ao   = xb;  // xb dead after proj GEMM

  auto cvt = [&](const float* s, unsigned short* d, int nelem) {
    const int nv = nelem >> 2;
    cvt_kernel<<<dim3((nv + 255) / 256), dim3(256), 0, stream>>>(s, d, nv);
  };
  cvt(x, xb, MROWS * CDIM);
  cvt(Wq1, Wall + 0,      64 * 1024);
  cvt(Wk1, Wall + 65536,  64 * 1024);
  cvt(Wq2, Wall + 131072, 128 * 1024);
  cvt(Wk2, Wall + 262144, 128 * 1024);
  cvt(Wv,  Wall + 393216, 1024 * 1024);
  cvt(Wo,  Wob,           1024 * 1024);

  gemm_bt<0><<<dim3(NPROJ / 128, MROWS / 128), dim3(256), 0, stream>>>(
      xb, Wall, proj, (float*)nullptr, (const float*)nullptr, MROWS, NPROJ, CDIM);

  kron_kernel<<<dim3(BATCH * HHEADS, NSEQ / 256), dim3(256), 0, stream>>>(proj, qf, kf);
  vtrans_kernel<<<dim3(NSEQ / 64, BATCH * HHEADS), dim3(256), 0, stream>>>(proj, vt);

  attn_split<<<dim3(1408), dim3(256), 0, stream>>>(qf, kf, vt, ao);

  gemm_bt<1><<<dim3(CDIM / 128, MROWS / 128), dim3(256), 0, stream>>>(
      ao, Wob, (unsigned short*)nullptr, out, bo, MROWS, CDIM, CDIM);
}

// Round 8
// 149.605 us; speedup vs baseline: 1.5798x; 1.5798x over previous
//
#include <hip/hip_runtime.h>

// ---------------- problem constants ----------------
#define HHEADS 16
#define R1 4
#define R2 8
#define HD 64
#define CDIM 1024
#define NSEQ 2048
#define BATCH 2
#define NPROJ 1408            // 64 q1 + 64 k1 + 128 q2 + 128 k2 + 1024 v
#define MROWS (BATCH * NSEQ)  // 4096
#define SCALE 0.17677669529663687f   // (R1*R2)^-0.5
#define SCALE_LOG2E 0.2550348612f    // SCALE * log2(e): scores in log2 domain

typedef __attribute__((ext_vector_type(8))) short bf16x8;
typedef __attribute__((ext_vector_type(4))) float f32x4;
typedef __attribute__((ext_vector_type(4))) unsigned int u32x4;

// ---------------- bf16 helpers (raw ushort representation) ----------------
__device__ __forceinline__ float bflo(unsigned u) { return __uint_as_float(u << 16); }
__device__ __forceinline__ float bfhi(unsigned u) { return __uint_as_float(u & 0xffff0000u); }
__device__ __forceinline__ unsigned short f2bfr(float f) {
  unsigned u = __float_as_uint(f);
  u += 0x7fffu + ((u >> 16) & 1u);
  return (unsigned short)(u >> 16);
}
__device__ __forceinline__ unsigned pack2(float a, float b) {
  return (unsigned)f2bfr(a) | ((unsigned)f2bfr(b) << 16);
}
// hardware packed f32x2 -> bf16x2 (RNE), single instruction (T12 recipe)
__device__ __forceinline__ unsigned cvtpk(float a, float b) {
  unsigned r;
  asm("v_cvt_pk_bf16_f32 %0, %1, %2" : "=v"(r) : "v"(a), "v"(b));
  return r;
}
// raw v_exp_f32 = 2^x (scores are kept in log2 domain)
__device__ __forceinline__ float exp2fast(float x) {
#if __has_builtin(__builtin_amdgcn_exp2f)
  return __builtin_amdgcn_exp2f(x);
#else
  float r;
  asm("v_exp_f32 %0, %1" : "=v"(r) : "v"(x));
  return r;
#endif
}

// ---------------- f32 -> bf16 conversion (vectorized) ----------------
__global__ void cvt_kernel(const float* __restrict__ src,
                           unsigned short* __restrict__ dst, int nvec) {
  for (int i = blockIdx.x * blockDim.x + threadIdx.x; i < nvec;
       i += gridDim.x * blockDim.x) {
    const float4 v = ((const float4*)src)[i];
    ushort4 o;
    o.x = f2bfr(v.x);
    o.y = f2bfr(v.y);
    o.z = f2bfr(v.z);
    o.w = f2bfr(v.w);
    ((ushort4*)dst)[i] = o;
  }
}

// ---------------- async global->LDS (16B per lane) ----------------
__device__ __forceinline__ void gld_lds16(const void* g, void* l) {
  __builtin_amdgcn_global_load_lds(
      (const __attribute__((address_space(1))) void*)g,
      (__attribute__((address_space(3))) void*)l, 16, 0, 0);
}

// ---------------- bf16 GEMM: C[M][N] = A[M][K] * Bw[N][K]^T ----------------
template <int OUTMODE>
__global__ __launch_bounds__(256) void gemm_bt(
    const unsigned short* __restrict__ A, const unsigned short* __restrict__ Bw,
    unsigned short* __restrict__ Cb, float* __restrict__ Cf,
    const float* __restrict__ bias, int M, int N, int K) {
  __shared__ unsigned short As[128 * 32];
  __shared__ unsigned short Bs[128 * 32];
  const int tid = threadIdx.x;
  const long brow = (long)blockIdx.y * 128;
  const long bcol = (long)blockIdx.x * 128;
  const int w = tid >> 6, lane = tid & 63;
  const int wr = w >> 1, wc = w & 1;
  const int lr = lane & 15, kg = lane >> 4;

  f32x4 acc[4][4];
#pragma unroll
  for (int m = 0; m < 4; ++m)
#pragma unroll
    for (int n = 0; n < 4; ++n) acc[m][n] = (f32x4){0.f, 0.f, 0.f, 0.f};

  const int off0 = tid * 16;
  const int row0 = off0 >> 6;
  const int kel0 = (off0 & 63) >> 1;

  const int nk = K >> 5;
  for (int kt = 0; kt < nk; ++kt) {
    const long kbase = (long)kt * 32 + kel0;
    gld_lds16(A + (brow + row0) * K + kbase, (char*)As + off0);
    gld_lds16(A + (brow + 64 + row0) * K + kbase, (char*)As + 4096 + off0);
    gld_lds16(Bw + (bcol + row0) * K + kbase, (char*)Bs + off0);
    gld_lds16(Bw + (bcol + 64 + row0) * K + kbase, (char*)Bs + 4096 + off0);
    __syncthreads();

    bf16x8 af[4], bfg[4];
#pragma unroll
    for (int m = 0; m < 4; ++m)
      af[m] = *(const bf16x8*)(As + (wr * 64 + m * 16 + lr) * 32 + kg * 8);
#pragma unroll
    for (int n = 0; n < 4; ++n)
      bfg[n] = *(const bf16x8*)(Bs + (wc * 64 + n * 16 + lr) * 32 + kg * 8);
#pragma unroll
    for (int m = 0; m < 4; ++m)
#pragma unroll
      for (int n = 0; n < 4; ++n)
        acc[m][n] = __builtin_amdgcn_mfma_f32_16x16x32_bf16(af[m], bfg[n],
                                                            acc[m][n], 0, 0, 0);
    __syncthreads();
  }

#pragma unroll
  for (int m = 0; m < 4; ++m) {
#pragma unroll
    for (int i = 0; i < 4; ++i) {
      const long r = brow + wr * 64 + m * 16 + kg * 4 + i;
#pragma unroll
      for (int n = 0; n < 4; ++n) {
        const long c = bcol + wc * 64 + n * 16 + lr;
        const float v = acc[m][n][i];
        if (OUTMODE == 1) {
          Cf[r * N + c] = v + bias[c];
        } else {
          Cb[r * N + c] = f2bfr(v);
        }
      }
    }
  }
}

// ---------------- kron feature build: qf/kf[bh][n][32] -------------------
// qf[r1*8+r2] = q1[r1]*q2[r2]*SCALE*log2e ; kf[r1*8+r2] = k1[r1]*k2[r2]
__global__ __launch_bounds__(256) void kron_kernel(
    const unsigned short* __restrict__ proj, unsigned short* __restrict__ qf,
    unsigned short* __restrict__ kf) {
  const int bh = blockIdx.x, b = bh >> 4, h = bh & 15;
  const int n = blockIdx.y * 256 + threadIdx.x;
  const unsigned short* row = proj + ((size_t)(b * NSEQ + n)) * NPROJ;
  float q1v[4], k1v[4], q2v[8], k2v[8];
  {
    const uint2 a = *(const uint2*)(row + h * 4);
    q1v[0] = bflo(a.x); q1v[1] = bfhi(a.x); q1v[2] = bflo(a.y); q1v[3] = bfhi(a.y);
    const uint2 c = *(const uint2*)(row + 64 + h * 4);
    k1v[0] = bflo(c.x); k1v[1] = bfhi(c.x); k1v[2] = bflo(c.y); k1v[3] = bfhi(c.y);
    const uint4 d = *(const uint4*)(row + 128 + h * 8);
    q2v[0] = bflo(d.x); q2v[1] = bfhi(d.x); q2v[2] = bflo(d.y); q2v[3] = bfhi(d.y);
    q2v[4] = bflo(d.z); q2v[5] = bfhi(d.z); q2v[6] = bflo(d.w); q2v[7] = bfhi(d.w);
    const uint4 e = *(const uint4*)(row + 256 + h * 8);
    k2v[0] = bflo(e.x); k2v[1] = bfhi(e.x); k2v[2] = bflo(e.y); k2v[3] = bfhi(e.y);
    k2v[4] = bflo(e.z); k2v[5] = bfhi(e.z); k2v[6] = bflo(e.w); k2v[7] = bfhi(e.w);
  }
  unsigned short* oq = qf + ((size_t)bh * NSEQ + n) * 32;
  unsigned short* ok = kf + ((size_t)bh * NSEQ + n) * 32;
#pragma unroll
  for (int i = 0; i < 4; ++i) {
    const float qs = q1v[i] * SCALE_LOG2E;
    uint4 uq, uk;
    uq.x = pack2(qs * q2v[0], qs * q2v[1]);
    uq.y = pack2(qs * q2v[2], qs * q2v[3]);
    uq.z = pack2(qs * q2v[4], qs * q2v[5]);
    uq.w = pack2(qs * q2v[6], qs * q2v[7]);
    uk.x = pack2(k1v[i] * k2v[0], k1v[i] * k2v[1]);
    uk.y = pack2(k1v[i] * k2v[2], k1v[i] * k2v[3]);
    uk.z = pack2(k1v[i] * k2v[4], k1v[i] * k2v[5]);
    uk.w = pack2(k1v[i] * k2v[6], k1v[i] * k2v[7]);
    *(uint4*)(oq + i * 8) = uq;
    *(uint4*)(ok + i * 8) = uk;
  }
}

// ---------------- V transpose: vt[bh][d][n] = proj[b,n][384+h*64+d] -------
__global__ __launch_bounds__(256) void vtrans_kernel(
    const unsigned short* __restrict__ proj, unsigned short* __restrict__ vt) {
  const int bh = blockIdx.y, b = bh >> 4, h = bh & 15;
  const int n0 = blockIdx.x * 64;
  const int tid = threadIdx.x;
#pragma unroll
  for (int it = 0; it < 2; ++it) {
    const int c = tid + it * 256;
    const int dd = c & 63;
    const int nn = (c >> 6) * 8;
    const unsigned short* src =
        proj + ((size_t)(b * NSEQ + n0 + nn)) * NPROJ + 384 + h * 64 + dd;
    unsigned short tmp[8];
#pragma unroll
    for (int j = 0; j < 8; ++j) tmp[j] = src[(size_t)j * NPROJ];
    uint4 u;
    u.x = (unsigned)tmp[0] | ((unsigned)tmp[1] << 16);
    u.y = (unsigned)tmp[2] | ((unsigned)tmp[3] << 16);
    u.z = (unsigned)tmp[4] | ((unsigned)tmp[5] << 16);
    u.w = (unsigned)tmp[6] | ((unsigned)tmp[7] << 16);
    *(uint4*)(vt + ((size_t)bh * 64 + dd) * NSEQ + n0 + nn) = u;
  }
}

// ---------------- MFMA flash attention: 4-wave blocks, in-block split-K ----
// 1408 blocks x 4 waves = 5632 waves, each <=16 key-tiles:
//  j in [0,32):  heavy block, qb = 63-j, 4 chunks (waves = chunks), LDS merge
//  j in [32,40): mid block m=j-32: item A qb=31-2m (waves 0,1), item B
//                qb=30-2m (waves 2,3), 2 chunks each, two LDS merges
//  j in [40,44): light block t=j-40: wave w -> qb = 15-(4t+w), direct write
// Non-leader chunks write unnormalized bf16 O + (m,l) to LDS (row pad 68
// kills the q-stride bank conflict); one barrier; leader does LSE merge.
// XCD affinity: bid&7 pins all 44 blocks of a head to one XCD (~1MB L2 set).
// NOTE: no min-waves launch bound — R7's (256,5) capped VGPR at 48 and
// spilled the accumulators to scratch (440 MB HBM traffic, 2.3x slower).
__global__ __launch_bounds__(256) void attn_split(
    const unsigned short* __restrict__ qf, const unsigned short* __restrict__ kf,
    const unsigned short* __restrict__ vt, unsigned short* __restrict__ ao) {
  __shared__ unsigned short o_part[3][32][68];
  __shared__ float st_part[3][32][2];

  const int bid = blockIdx.x;
  const int xcd = bid & 7;
  const int idx = bid >> 3;        // [0,176) per XCD
  const int g = idx / 44;          // head group [0,4)
  const int j = idx - g * 44;      // [0,44)
  const int bh = g * 8 + xcd;      // all 44 blocks of bh on one XCD
  const int w = threadIdx.x >> 6;
  const int lane = threadIdx.x & 63;

  int qb, nw, c;
  if (j < 32) {
    qb = 63 - j; nw = 4; c = w;
  } else if (j < 40) {
    const int m = j - 32;
    nw = 2;
    if (w < 2) { qb = 31 - 2 * m; c = w; }
    else       { qb = 30 - 2 * m; c = w - 2; }
  } else {
    const int t = j - 40;
    qb = 15 - (t * 4 + w); nw = 1; c = 0;
  }
  const int T = qb + 1;                       // total key tiles for this qb
  const int tb = (c * T) / nw, te = ((c + 1) * T) / nw;
  const int nt = te - tb;                     // tiles in this chunk (>=1)
  const int k_lo = tb * 32;
  const bool domask = (c == nw - 1);
  const bool is_leader = (nw > 1) && (c == 0);
  const bool is_partial = (nw > 1) && (c > 0);
  const int slot = w - 1;                     // partial waves: LDS slot
  const int s_begin = (nw == 4) ? 0 : w;      // leader's slot range
  const int s_end = (nw == 4) ? 3 : w + 1;

  const int qbase = qb * 32;
  const int lr = lane & 15, kg = lane >> 4;
  const int b = bh >> 4, h = bh & 15;
  const int q0 = qbase + lr;
  const int q1 = qbase + 16 + lr;

  const unsigned short* qfh = qf + (size_t)bh * NSEQ * 32;
  const unsigned short* kfh = kf + (size_t)bh * NSEQ * 32 + (size_t)k_lo * 32;
  const unsigned short* vth = vt + (size_t)bh * 64 * NSEQ + k_lo;

  const bf16x8 qA = *(const bf16x8*)(qfh + q0 * 32 + kg * 8);
  const bf16x8 qB = *(const bf16x8*)(qfh + q1 * 32 + kg * 8);
  const int krow = (lr >> 2) * 8 + (lr & 3);  // permuted key row for A-frag
  const int kof0 = krow * 32 + kg * 8;
  const int kof1 = kof0 + 4 * 32;
  const int vof0 = (0 * 16 + lr) * NSEQ + kg * 8;
  const int vof1 = (1 * 16 + lr) * NSEQ + kg * 8;
  const int vof2 = (2 * 16 + lr) * NSEQ + kg * 8;
  const int vof3 = (3 * 16 + lr) * NSEQ + kg * 8;
  const f32x4 zero = (f32x4){0.f, 0.f, 0.f, 0.f};

  f32x4 oA[4], oB[4];
#pragma unroll
  for (int dt = 0; dt < 4; ++dt) { oA[dt] = zero; oB[dt] = zero; }
  float mA = -1e30f, mB = -1e30f, lAs = 0.f, lBs = 0.f;

  // prime the pipeline: tile 0 fragments
  bf16x8 ck0 = *(const bf16x8*)(kfh + kof0);
  bf16x8 ck1 = *(const bf16x8*)(kfh + kof1);
  bf16x8 cv0 = *(const bf16x8*)(vth + vof0);
  bf16x8 cv1 = *(const bf16x8*)(vth + vof1);
  bf16x8 cv2 = *(const bf16x8*)(vth + vof2);
  bf16x8 cv3 = *(const bf16x8*)(vth + vof3);

  for (int kt = 0; kt < nt; ++kt) {
    // ---- issue next tile's loads (clamped; last iter re-loads, harmless)
    const int kn = (kt + 1 < nt ? kt + 1 : nt - 1) * 32;
    const bf16x8 nk0 = *(const bf16x8*)(kfh + kn * 32 + kof0);
    const bf16x8 nk1 = *(const bf16x8*)(kfh + kn * 32 + kof1);
    const bf16x8 nv0 = *(const bf16x8*)(vth + vof0 + kn);
    const bf16x8 nv1 = *(const bf16x8*)(vth + vof1 + kn);
    const bf16x8 nv2 = *(const bf16x8*)(vth + vof2 + kn);
    const bf16x8 nv3 = *(const bf16x8*)(vth + vof3 + kn);

    // ---- scores (log2 domain): s{A,B}0[i] = S[key k_lo+kt*32+kg*8+i][q]
    f32x4 sA0 = __builtin_amdgcn_mfma_f32_16x16x32_bf16(ck0, qA, zero, 0, 0, 0);
    f32x4 sA1 = __builtin_amdgcn_mfma_f32_16x16x32_bf16(ck1, qA, zero, 0, 0, 0);
    f32x4 sB0 = __builtin_amdgcn_mfma_f32_16x16x32_bf16(ck0, qB, zero, 0, 0, 0);
    f32x4 sB1 = __builtin_amdgcn_mfma_f32_16x16x32_bf16(ck1, qB, zero, 0, 0, 0);

    if (domask && kt == nt - 1) {  // diagonal tile: causal mask
      const int kb = k_lo + kt * 32 + kg * 8;
#pragma unroll
      for (int i = 0; i < 4; ++i) {
        if (kb + i > q0) sA0[i] = -1e30f;
        if (kb + 4 + i > q0) sA1[i] = -1e30f;
        if (kb + i > q1) sB0[i] = -1e30f;
        if (kb + 4 + i > q1) sB1[i] = -1e30f;
      }
    }

    // ---- lane-local max check; cross-lane reduce ONLY on growth
    const float mxA = fmaxf(fmaxf(fmaxf(sA0[0], sA0[1]), fmaxf(sA0[2], sA0[3])),
                            fmaxf(fmaxf(sA1[0], sA1[1]), fmaxf(sA1[2], sA1[3])));
    const float mxB = fmaxf(fmaxf(fmaxf(sB0[0], sB0[1]), fmaxf(sB0[2], sB0[3])),
                            fmaxf(fmaxf(sB1[0], sB1[1]), fmaxf(sB1[2], sB1[3])));
    const bool ok = (mxA <= mA + 8.f) && (mxB <= mB + 8.f);
    if (!__all(ok)) {
      float rA = fmaxf(mxA, __shfl_xor(mxA, 16));
      rA = fmaxf(rA, __shfl_xor(rA, 32));
      float rB = fmaxf(mxB, __shfl_xor(mxB, 16));
      rB = fmaxf(rB, __shfl_xor(rB, 32));
      const float nmA = fmaxf(mA, rA), nmB = fmaxf(mB, rB);
      const float cA = exp2fast(mA - nmA), cB = exp2fast(mB - nmB);
      mA = nmA; mB = nmB;
      lAs *= cA; lBs *= cB;
#pragma unroll
      for (int dt = 0; dt < 4; ++dt) {
        oA[dt][0] *= cA; oA[dt][1] *= cA; oA[dt][2] *= cA; oA[dt][3] *= cA;
        oB[dt][0] *= cB; oB[dt][1] *= cB; oB[dt][2] *= cB; oB[dt][3] *= cB;
      }
    }

    const float a0 = exp2fast(sA0[0] - mA), a1 = exp2fast(sA0[1] - mA);
    const float a2 = exp2fast(sA0[2] - mA), a3 = exp2fast(sA0[3] - mA);
    const float a4 = exp2fast(sA1[0] - mA), a5 = exp2fast(sA1[1] - mA);
    const float a6 = exp2fast(sA1[2] - mA), a7 = exp2fast(sA1[3] - mA);
    const float b0 = exp2fast(sB0[0] - mB), b1 = exp2fast(sB0[1] - mB);
    const float b2 = exp2fast(sB0[2] - mB), b3 = exp2fast(sB0[3] - mB);
    const float b4 = exp2fast(sB1[0] - mB), b5 = exp2fast(sB1[1] - mB);
    const float b6 = exp2fast(sB1[2] - mB), b7 = exp2fast(sB1[3] - mB);
    lAs += ((a0 + a1) + (a2 + a3)) + ((a4 + a5) + (a6 + a7));
    lBs += ((b0 + b1) + (b2 + b3)) + ((b4 + b5) + (b6 + b7));

    union { u32x4 u; bf16x8 hv; } pA, pB;
    pA.u = (u32x4){cvtpk(a0, a1), cvtpk(a2, a3), cvtpk(a4, a5), cvtpk(a6, a7)};
    pB.u = (u32x4){cvtpk(b0, b1), cvtpk(b2, b3), cvtpk(b4, b5), cvtpk(b6, b7)};

    oA[0] = __builtin_amdgcn_mfma_f32_16x16x32_bf16(cv0, pA.hv, oA[0], 0, 0, 0);
    oB[0] = __builtin_amdgcn_mfma_f32_16x16x32_bf16(cv0, pB.hv, oB[0], 0, 0, 0);
    oA[1] = __builtin_amdgcn_mfma_f32_16x16x32_bf16(cv1, pA.hv, oA[1], 0, 0, 0);
    oB[1] = __builtin_amdgcn_mfma_f32_16x16x32_bf16(cv1, pB.hv, oB[1], 0, 0, 0);
    oA[2] = __builtin_amdgcn_mfma_f32_16x16x32_bf16(cv2, pA.hv, oA[2], 0, 0, 0);
    oB[2] = __builtin_amdgcn_mfma_f32_16x16x32_bf16(cv2, pB.hv, oB[2], 0, 0, 0);
    oA[3] = __builtin_amdgcn_mfma_f32_16x16x32_bf16(cv3, pA.hv, oA[3], 0, 0, 0);
    oB[3] = __builtin_amdgcn_mfma_f32_16x16x32_bf16(cv3, pB.hv, oB[3], 0, 0, 0);

    ck0 = nk0; ck1 = nk1;
    cv0 = nv0; cv1 = nv1; cv2 = nv2; cv3 = nv3;
  }

  // per-q softmax denominator (reduce partial lsum across kg groups)
  float ltA = lAs + __shfl_xor(lAs, 16);
  ltA += __shfl_xor(ltA, 32);
  float ltB = lBs + __shfl_xor(lBs, 16);
  ltB += __shfl_xor(ltB, 32);

  if (is_partial) {  // write unnormalized bf16 O + (m,l) to LDS
#pragma unroll
    for (int dt = 0; dt < 4; ++dt) {
      uint2 ua, ub;
      ua.x = pack2(oA[dt][0], oA[dt][1]);
      ua.y = pack2(oA[dt][2], oA[dt][3]);
      ub.x = pack2(oB[dt][0], oB[dt][1]);
      ub.y = pack2(oB[dt][2], oB[dt][3]);
      *(uint2*)(&o_part[slot][lr][dt * 16 + kg * 4]) = ua;
      *(uint2*)(&o_part[slot][16 + lr][dt * 16 + kg * 4]) = ub;
    }
    if (kg == 0) {
      st_part[slot][lr][0] = mA;
      st_part[slot][lr][1] = ltA;
      st_part[slot][16 + lr][0] = mB;
      st_part[slot][16 + lr][1] = ltB;
    }
  }
  __syncthreads();

  if (is_leader) {  // LSE merge of own chunk + slots [s_begin, s_end)
    float M_A = mA, M_B = mB;
    for (int s = s_begin; s < s_end; ++s) {
      M_A = fmaxf(M_A, st_part[s][lr][0]);
      M_B = fmaxf(M_B, st_part[s][16 + lr][0]);
    }
    const float f0A = exp2fast(mA - M_A), f0B = exp2fast(mB - M_B);
    float L_A = ltA * f0A, L_B = ltB * f0B;
#pragma unroll
    for (int dt = 0; dt < 4; ++dt) {
      oA[dt][0] *= f0A; oA[dt][1] *= f0A; oA[dt][2] *= f0A; oA[dt][3] *= f0A;
      oB[dt][0] *= f0B; oB[dt][1] *= f0B; oB[dt][2] *= f0B; oB[dt][3] *= f0B;
    }
    for (int s = s_begin; s < s_end; ++s) {
      const float fsA = exp2fast(st_part[s][lr][0] - M_A);
      const float fsB = exp2fast(st_part[s][16 + lr][0] - M_B);
      L_A += st_part[s][lr][1] * fsA;
      L_B += st_part[s][16 + lr][1] * fsB;
#pragma unroll
      for (int dt = 0; dt < 4; ++dt) {
        const uint2 ua = *(const uint2*)(&o_part[s][lr][dt * 16 + kg * 4]);
        oA[dt][0] += bflo(ua.x) * fsA; oA[dt][1] += bfhi(ua.x) * fsA;
        oA[dt][2] += bflo(ua.y) * fsA; oA[dt][3] += bfhi(ua.y) * fsA;
        const uint2 ub = *(const uint2*)(&o_part[s][16 + lr][dt * 16 + kg * 4]);
        oB[dt][0] += bflo(ub.x) * fsB; oB[dt][1] += bfhi(ub.x) * fsB;
        oB[dt][2] += bflo(ub.y) * fsB; oB[dt][3] += bfhi(ub.y) * fsB;
      }
    }
    const float invA = 1.f / L_A, invB = 1.f / L_B;
    unsigned short* pAo = ao + ((size_t)(b * NSEQ + q0)) * CDIM + h * 64 + kg * 4;
    unsigned short* pBo = ao + ((size_t)(b * NSEQ + q1)) * CDIM + h * 64 + kg * 4;
#pragma unroll
    for (int dt = 0; dt < 4; ++dt) {
      uint2 ua, ub;
      ua.x = pack2(oA[dt][0] * invA, oA[dt][1] * invA);
      ua.y = pack2(oA[dt][2] * invA, oA[dt][3] * invA);
      ub.x = pack2(oB[dt][0] * invB, oB[dt][1] * invB);
      ub.y = pack2(oB[dt][2] * invB, oB[dt][3] * invB);
      *(uint2*)(pAo + dt * 16) = ua;
      *(uint2*)(pBo + dt * 16) = ub;
    }
  } else if (nw == 1) {  // light items: direct normalized write
    const float invA = 1.f / ltA, invB = 1.f / ltB;
    unsigned short* pAo = ao + ((size_t)(b * NSEQ + q0)) * CDIM + h * 64 + kg * 4;
    unsigned short* pBo = ao + ((size_t)(b * NSEQ + q1)) * CDIM + h * 64 + kg * 4;
#pragma unroll
    for (int dt = 0; dt < 4; ++dt) {
      uint2 ua, ub;
      ua.x = pack2(oA[dt][0] * invA, oA[dt][1] * invA);
      ua.y = pack2(oA[dt][2] * invA, oA[dt][3] * invA);
      ub.x = pack2(oB[dt][0] * invB, oB[dt][1] * invB);
      ub.y = pack2(oB[dt][2] * invB, oB[dt][3] * invB);
      *(uint2*)(pAo + dt * 16) = ua;
      *(uint2*)(pBo + dt * 16) = ub;
    }
  }
}

// ---------------- launch ----------------
extern "C" void kernel_launch(void* const* d_in, const int* in_sizes, int n_in,
                              void* d_out, int out_size, void* d_ws,
                              size_t ws_size, hipStream_t stream) {
  (void)in_sizes; (void)n_in; (void)out_size; (void)ws_size;
  const float* x   = (const float*)d_in[0];
  const float* Wq1 = (const float*)d_in[1];
  const float* Wk1 = (const float*)d_in[2];
  const float* Wq2 = (const float*)d_in[3];
  const float* Wk2 = (const float*)d_in[4];
  const float* Wv  = (const float*)d_in[5];
  const float* Wo  = (const float*)d_in[6];
  const float* bo  = (const float*)d_in[7];
  float* out = (float*)d_out;

  char* ws = (char*)d_ws;
  unsigned short* xb   = (unsigned short*)(ws);              // 8 MB (reused as ao)
  unsigned short* Wall = (unsigned short*)(ws + 8388608);    // 2,883,584 B
  unsigned short* Wob  = (unsigned short*)(ws + 11272192);   // 2 MB
  unsigned short* proj = (unsigned short*)(ws + 13369344);   // 11,534,336 B
  unsigned short* qf   = (unsigned short*)(ws + 24903680);   // 4 MB
  unsigned short* kf   = (unsigned short*)(ws + 29097984);   // 4 MB
  unsigned short* vt   = (unsigned short*)(ws + 33292288);   // 8 MB
  unsigned short* ao   = xb;  // xb dead after proj GEMM

  auto cvt = [&](const float* s, unsigned short* d, int nelem) {
    const int nv = nelem >> 2;
    cvt_kernel<<<dim3((nv + 255) / 256), dim3(256), 0, stream>>>(s, d, nv);
  };
  cvt(x, xb, MROWS * CDIM);
  cvt(Wq1, Wall + 0,      64 * 1024);
  cvt(Wk1, Wall + 65536,  64 * 1024);
  cvt(Wq2, Wall + 131072, 128 * 1024);
  cvt(Wk2, Wall + 262144, 128 * 1024);
  cvt(Wv,  Wall + 393216, 1024 * 1024);
  cvt(Wo,  Wob,           1024 * 1024);

  gemm_bt<0><<<dim3(NPROJ / 128, MROWS / 128), dim3(256), 0, stream>>>(
      xb, Wall, proj, (float*)nullptr, (const float*)nullptr, MROWS, NPROJ, CDIM);

  kron_kernel<<<dim3(BATCH * HHEADS, NSEQ / 256), dim3(256), 0, stream>>>(proj, qf, kf);
  vtrans_kernel<<<dim3(NSEQ / 64, BATCH * HHEADS), dim3(256), 0, stream>>>(proj, vt);

  attn_split<<<dim3(1408), dim3(256), 0, stream>>>(qf, kf, vt, ao);

  gemm_bt<1><<<dim3(CDIM / 128, MROWS / 128), dim3(256), 0, stream>>>(
      ao, Wob, (unsigned short*)nullptr, out, bo, MROWS, CDIM, CDIM);
}